// Round 1
// baseline (5617.432 us; speedup 1.0000x reference)
//
#include <hip/hip_runtime.h>
#include <math.h>

// Problem constants (B=2, N=1024, DE=1024, H=16, DH=64 complex dims/head)
#define BB      2
#define NN      1024
#define DE_     1024
#define HH      16
#define DHC     64          // complex dims per head == wavefront size
#define DKK     1024        // H * DHC
#define TWO_DK  2048

// ---------------------------------------------------------------------------
// fp32 tiled GEMM: C[M,NC] = A[M,K] @ W[K,NC], 64x64 tile, 256 thr, 4x4 micro
// ---------------------------------------------------------------------------
template<int K, int NC>
__device__ __forceinline__ void gemm_body(const float* __restrict__ A,
                                          const float* __restrict__ W,
                                          float* __restrict__ C) {
    __shared__ float sA[16][65];   // [k][m], +1 pad
    __shared__ float sB[16][65];   // [k][n]
    const int tx   = threadIdx.x;
    const int m0   = blockIdx.x * 64;
    const int n0   = blockIdx.y * 64;
    const int trow = tx >> 4;      // 0..15
    const int tcol = tx & 15;      // 0..15
    const int nn   = tx & 63;      // 0..63 (B-load col)
    const int kr0  = tx >> 6;      // 0..3  (B-load k base)

    float acc[4][4] = {{0.f}};

    for (int k0 = 0; k0 < K; k0 += 16) {
#pragma unroll
        for (int mm = 0; mm < 4; ++mm)
            sA[tcol][trow + mm * 16] =
                A[(size_t)(m0 + trow + mm * 16) * K + (k0 + tcol)];
#pragma unroll
        for (int kk = 0; kk < 4; ++kk)
            sB[kr0 + kk * 4][nn] =
                W[(size_t)(k0 + kr0 + kk * 4) * NC + (n0 + nn)];
        __syncthreads();
#pragma unroll
        for (int kk = 0; kk < 16; ++kk) {
            float av[4], bv[4];
#pragma unroll
            for (int a = 0; a < 4; ++a) av[a] = sA[kk][trow * 4 + a];
#pragma unroll
            for (int b = 0; b < 4; ++b) bv[b] = sB[kk][tcol * 4 + b];
#pragma unroll
            for (int a = 0; a < 4; ++a)
#pragma unroll
                for (int b = 0; b < 4; ++b)
                    acc[a][b] = fmaf(av[a], bv[b], acc[a][b]);
        }
        __syncthreads();
    }
#pragma unroll
    for (int a = 0; a < 4; ++a) {
        float4 r = make_float4(acc[a][0], acc[a][1], acc[a][2], acc[a][3]);
        *(float4*)(&C[(size_t)(m0 + trow * 4 + a) * NC + (n0 + tcol * 4)]) = r;
    }
}

// q/k/v = x @ Wq/Wk/Wv : M=2048, K=1024(DE), NC=2048. grid.z selects stream.
__global__ __launch_bounds__(256) void gemm_qkv(
    const float* __restrict__ x,
    const float* __restrict__ Wq, const float* __restrict__ Wk,
    const float* __restrict__ Wv,
    float* __restrict__ q, float* __restrict__ k, float* __restrict__ v) {
    const float* W = (blockIdx.z == 0) ? Wq : (blockIdx.z == 1) ? Wk : Wv;
    float*       o = (blockIdx.z == 0) ? q  : (blockIdx.z == 1) ? k  : v;
    gemm_body<DE_, TWO_DK>(x, W, o);
}

// out = y @ Wo : M=2048, K=2048, NC=1024
__global__ __launch_bounds__(256) void gemm_out(
    const float* __restrict__ y, const float* __restrict__ Wo,
    float* __restrict__ out) {
    gemm_body<TWO_DK, DE_>(y, Wo, out);
}

// ---------------------------------------------------------------------------
// In-place RoPE rotation of q and k + per-(b,h,n) squared norms qn/kn.
// Layout of q/k/v: [B, N, 2*DK] packed: [0:1024) real (h*64+d), [1024:2048) imag.
// One block per (b,n); thread t handles complex elems 4t..4t+3 (same head).
// ---------------------------------------------------------------------------
__global__ __launch_bounds__(256) void rotate_norm(
    float* __restrict__ q, float* __restrict__ k,
    const float* __restrict__ omega,
    float* __restrict__ qn, float* __restrict__ kn) {
    const int bn = blockIdx.x;
    const int b  = bn >> 10;         // / N
    const int n  = bn & (NN - 1);
    const int t  = threadIdx.x;
    float* qp = q + (size_t)bn * TWO_DK;
    float* kp = k + (size_t)bn * TWO_DK;
    float qsum = 0.f, ksum = 0.f;
#pragma unroll
    for (int e0 = 0; e0 < 4; ++e0) {
        const int e = t * 4 + e0;    // complex index 0..1023
        const int h = e >> 6;
        const int d = e & 63;
        // om stacked [omega, -omega] along d
        const float om  = (d < 32) ? omega[h * 32 + d] : -omega[h * 32 + (d - 32)];
        const float ang = (float)n * om;
        float sn, cs;
        sincosf(ang, &sn, &cs);
        const float qre = qp[e], qim = qp[DKK + e];
        const float kre = kp[e], kim = kp[DKK + e];
        qsum = fmaf(qre, qre, fmaf(qim, qim, qsum));
        ksum = fmaf(kre, kre, fmaf(kim, kim, ksum));
        qp[e]       = qre * cs - qim * sn;
        qp[DKK + e] = qre * sn + qim * cs;
        kp[e]       = kre * cs - kim * sn;
        kp[DKK + e] = kre * sn + kim * cs;
    }
    // 16-lane segmented reduction (one head per 16 consecutive lanes)
#pragma unroll
    for (int msk = 1; msk < 16; msk <<= 1) {
        qsum += __shfl_xor(qsum, msk);
        ksum += __shfl_xor(ksum, msk);
    }
    const int lane = t & 63;
    if ((lane & 15) == 0) {
        const int wave = t >> 6;
        const int h    = wave * 4 + (lane >> 4);
        qn[((size_t)b * HH + h) * NN + n] = qsum;
        kn[((size_t)b * HH + h) * NN + n] = ksum;
    }
}

// ---------------------------------------------------------------------------
// Attention: one wave per output row i (lane = complex dim d, DHC==64==wave).
// Block = 4 waves = 4 rows of one (b,h). dt-dependent terms (E, 1/V, -32logV)
// precomputed into LDS tables once per block. Online softmax; y aliases q.
// ---------------------------------------------------------------------------
__global__ __launch_bounds__(256) void attn(
    const float* __restrict__ qr, const float* __restrict__ kr,
    const float* __restrict__ v,
    const float* __restrict__ qn, const float* __restrict__ kn,
    const float* __restrict__ mu_raw, const float* __restrict__ sigma_raw,
    const float* __restrict__ eta_raw, const float* __restrict__ gamma_raw,
    const float* __restrict__ tau, const float* __restrict__ nu_raw,
    float* __restrict__ y) {
    __shared__ float sE[NN];     // exp(clip(-mu*dt, -30, 0))
    __shared__ float sIV[NN];    // 1/V(dt)
    __shared__ float sBase[NN];  // -0.5*DH*log(V) = -32*log V

    const int bh = blockIdx.y;
    const int b  = bh >> 4;
    const int h  = bh & 15;

    // per-head scalars (redundant per thread; trivial cost)
    const float mu     = 1.f / (1.f + expf(-mu_raw[h])) + 1e-4f;
    const float sig    = log1pf(expf(sigma_raw[h]));   // softplus
    const float eta    = log1pf(expf(eta_raw[h]));
    const float gam    = log1pf(expf(gamma_raw[h]));
    const float Ac     = sig / (2.f * mu);
    const float Cc     = eta + gam;
    const float nu     = log1pf(expf(nu_raw[h]));
    const float coef   = -0.5f * tau[h] * (nu + 64.0f);  // DH_ = 64
    const float inv_nu = 1.f / nu;

    for (int dt = threadIdx.x; dt < NN; dt += 256) {
        const float arg = fmaxf(-mu * (float)dt, -30.0f);
        const float E   = expf(arg);
        const float V   = fmaf(Ac, 1.f - E * E, Cc);
        sE[dt]    = E;
        sIV[dt]   = 1.f / V;
        sBase[dt] = -32.f * logf(V);
    }
    __syncthreads();

    const int wave = threadIdx.x >> 6;
    const int lane = threadIdx.x & 63;
    const int i    = blockIdx.x * 4 + wave;

    const size_t rowq = ((size_t)(b * NN + i)) * TWO_DK + h * DHC;
    const float  qre  = qr[rowq + lane];
    const float  qim  = qr[rowq + DKK + lane];
    const float  qni  = qn[(size_t)bh * NN + i];

    const float* kb  = kr + ((size_t)b * NN) * TWO_DK + h * DHC;
    const float* vb  = v  + ((size_t)b * NN) * TWO_DK + h * DHC;
    const float* knb = kn + (size_t)bh * NN;

    float m = -INFINITY, l = 0.f, o_r = 0.f, o_i = 0.f;
    for (int j = 0; j <= i; ++j) {
        const float* kp = kb + (size_t)j * TWO_DK;
        const float* vp = vb + (size_t)j * TWO_DK;
        // Re<qr_i, conj(kr_j)> partial: qr_r*kr_r + qr_i*kr_i
        float p = fmaf(qre, kp[lane], qim * kp[DKK + lane]);
#pragma unroll
        for (int msk = 1; msk < 64; msk <<= 1) p += __shfl_xor(p, msk);

        const int   dt    = i - j;
        const float E     = sE[dt];
        const float maha  = fmaxf(fmaf(E * E, knb[j], qni) - 2.f * E * p, 0.f) * sIV[dt];
        const float logit = fmaf(coef, log1pf(maha * inv_nu), sBase[dt]);

        const float mn    = fmaxf(m, logit);
        const float alpha = expf(m - mn);      // first iter: exp(-inf)=0
        const float w     = expf(logit - mn);
        l   = fmaf(l, alpha, w);
        o_r = fmaf(o_r, alpha, w * vp[lane]);
        o_i = fmaf(o_i, alpha, w * vp[DKK + lane]);
        m   = mn;
    }
    const float invl = 1.f / l;
    // y aliases q: this wave's slice of row i was fully consumed above.
    y[rowq + lane]       = o_r * invl;
    y[rowq + DKK + lane] = o_i * invl;
}

// ---------------------------------------------------------------------------
extern "C" void kernel_launch(void* const* d_in, const int* in_sizes, int n_in,
                              void* d_out, int out_size, void* d_ws, size_t ws_size,
                              hipStream_t stream) {
    const float* x         = (const float*)d_in[0];
    const float* Wq        = (const float*)d_in[1];
    const float* Wk        = (const float*)d_in[2];
    const float* Wv        = (const float*)d_in[3];
    const float* Wo        = (const float*)d_in[4];
    const float* omega     = (const float*)d_in[5];
    const float* mu_raw    = (const float*)d_in[6];
    const float* sigma_raw = (const float*)d_in[7];
    const float* eta_raw   = (const float*)d_in[8];
    const float* gamma_raw = (const float*)d_in[9];
    const float* tau       = (const float*)d_in[10];
    const float* nu_raw    = (const float*)d_in[11];
    float* out = (float*)d_out;

    // workspace layout (floats): q | k | v | qn | kn  (~48.3 MB total)
    float* q  = (float*)d_ws;
    float* k  = q  + (size_t)BB * NN * TWO_DK;
    float* v  = k  + (size_t)BB * NN * TWO_DK;
    float* qn = v  + (size_t)BB * NN * TWO_DK;
    float* kn = qn + (size_t)BB * HH * NN;

    // 1) q,k,v = x @ {Wq,Wk,Wv}
    gemm_qkv<<<dim3(32, 32, 3), 256, 0, stream>>>(x, Wq, Wk, Wv, q, k, v);
    // 2) rotate q,k in place; emit per-head norms
    rotate_norm<<<dim3(BB * NN), 256, 0, stream>>>(q, k, omega, qn, kn);
    // 3) fused scores + online softmax + A·v ; y overwrites q
    attn<<<dim3(NN / 4, BB * HH), 256, 0, stream>>>(
        q, k, v, qn, kn, mu_raw, sigma_raw, eta_raw, gamma_raw, tau, nu_raw, q);
    // 4) out = y @ Wo
    gemm_out<<<dim3(32, 16), 256, 0, stream>>>(q, Wo, out);
}

// Round 2
// 1079.956 us; speedup vs baseline: 5.2015x; 5.2015x over previous
//
#include <hip/hip_runtime.h>
#include <math.h>

// Problem constants (B=2, N=1024, DE=1024, H=16, DH=64 complex dims/head)
#define BB      2
#define NN      1024
#define DE_     1024
#define HH      16
#define DKK     1024        // H * DHC
#define TWO_DK  2048
#define DD      128         // per-head feature dim (re||im)
#define PADR    68          // LDS row stride (floats) for 64-wide tiles

// ---------------------------------------------------------------------------
// QKV GEMM: q/k/v = x @ W, stored packed per-head: o[((b*16+h)*1024+n)*128 + d]
// (real at d<64, imag at d+64). 64x64 tile, 256 thr, 4x4 microtile, fp32.
// ---------------------------------------------------------------------------
__global__ __launch_bounds__(256) void gemm_qkv_pack(
    const float* __restrict__ x,
    const float* __restrict__ Wq, const float* __restrict__ Wk,
    const float* __restrict__ Wv,
    float* __restrict__ qp, float* __restrict__ kp, float* __restrict__ vp) {
    __shared__ float sA[16][65];
    __shared__ float sB[16][65];
    const int tx = threadIdx.x;
    const int m0 = blockIdx.x * 64;
    const int n0 = blockIdx.y * 64;
    const float* W = (blockIdx.z == 0) ? Wq : (blockIdx.z == 1) ? Wk : Wv;
    float*       o = (blockIdx.z == 0) ? qp : (blockIdx.z == 1) ? kp : vp;
    const int trow = tx >> 4, tcol = tx & 15;
    const int nn = tx & 63, kr0 = tx >> 6;
    float acc[4][4] = {{0.f}};

    for (int k0 = 0; k0 < DE_; k0 += 16) {
#pragma unroll
        for (int mm = 0; mm < 4; ++mm)
            sA[tcol][trow + mm * 16] = x[(size_t)(m0 + trow + mm * 16) * DE_ + k0 + tcol];
#pragma unroll
        for (int kk = 0; kk < 4; ++kk)
            sB[kr0 + kk * 4][nn] = W[(size_t)(k0 + kr0 + kk * 4) * TWO_DK + n0 + nn];
        __syncthreads();
#pragma unroll
        for (int kk = 0; kk < 16; ++kk) {
            float av[4], bv[4];
#pragma unroll
            for (int a = 0; a < 4; ++a) av[a] = sA[kk][trow * 4 + a];
#pragma unroll
            for (int b = 0; b < 4; ++b) bv[b] = sB[kk][tcol * 4 + b];
#pragma unroll
            for (int a = 0; a < 4; ++a)
#pragma unroll
                for (int b = 0; b < 4; ++b)
                    acc[a][b] = fmaf(av[a], bv[b], acc[a][b]);
        }
        __syncthreads();
    }
    const int col0 = n0 + tcol * 4;          // column in [0,2048)
    const int im   = col0 >> 10;             // 0 = real, 1 = imag
    const int hh   = (col0 & 1023) >> 6;
    const int d0   = col0 & 63;
#pragma unroll
    for (int a = 0; a < 4; ++a) {
        const int m  = m0 + trow * 4 + a;
        const int bb = m >> 10, n2 = m & 1023;
        float4 r = make_float4(acc[a][0], acc[a][1], acc[a][2], acc[a][3]);
        *(float4*)&o[(((size_t)bb * HH + hh) * NN + n2) * DD + im * 64 + d0] = r;
    }
}

// ---------------------------------------------------------------------------
// Output GEMM: out[B,N,DE] = y @ Wo, where y is read from packed layout
// yp[((b*16+h)*1024+n)*128 + d] (re d<64, im d+64) via remapped A-load.
// ---------------------------------------------------------------------------
__global__ __launch_bounds__(256) void gemm_out_remap(
    const float* __restrict__ yp, const float* __restrict__ Wo,
    float* __restrict__ out) {
    __shared__ float sA[16][65];
    __shared__ float sB[16][65];
    const int tx = threadIdx.x;
    const int m0 = blockIdx.x * 64;
    const int n0 = blockIdx.y * 64;
    const int trow = tx >> 4, tcol = tx & 15;
    const int nn = tx & 63, kr0 = tx >> 6;
    float acc[4][4] = {{0.f}};

    for (int k0 = 0; k0 < TWO_DK; k0 += 16) {
        const int km = k0 + tcol;
        const int im = km >> 10, hh = (km & 1023) >> 6, d = km & 63;
#pragma unroll
        for (int mm = 0; mm < 4; ++mm) {
            const int m  = m0 + trow + mm * 16;
            const int bb = m >> 10, n2 = m & 1023;
            sA[tcol][trow + mm * 16] =
                yp[(((size_t)bb * HH + hh) * NN + n2) * DD + im * 64 + d];
        }
#pragma unroll
        for (int kk = 0; kk < 4; ++kk)
            sB[kr0 + kk * 4][nn] = Wo[(size_t)(k0 + kr0 + kk * 4) * DE_ + n0 + nn];
        __syncthreads();
#pragma unroll
        for (int kk = 0; kk < 16; ++kk) {
            float av[4], bv[4];
#pragma unroll
            for (int a = 0; a < 4; ++a) av[a] = sA[kk][trow * 4 + a];
#pragma unroll
            for (int b = 0; b < 4; ++b) bv[b] = sB[kk][tcol * 4 + b];
#pragma unroll
            for (int a = 0; a < 4; ++a)
#pragma unroll
                for (int b = 0; b < 4; ++b)
                    acc[a][b] = fmaf(av[a], bv[b], acc[a][b]);
        }
        __syncthreads();
    }
#pragma unroll
    for (int a = 0; a < 4; ++a) {
        float4 r = make_float4(acc[a][0], acc[a][1], acc[a][2], acc[a][3]);
        *(float4*)&out[(size_t)(m0 + trow * 4 + a) * DE_ + (n0 + tcol * 4)] = r;
    }
}

// ---------------------------------------------------------------------------
// In-place RoPE rotation of packed qp/kp rows + per-row squared norms.
// One wave per row (lane = complex dim d).
// ---------------------------------------------------------------------------
__global__ __launch_bounds__(256) void rotate_qk(
    float* __restrict__ qp, float* __restrict__ kp,
    const float* __restrict__ omega,
    float* __restrict__ qn_, float* __restrict__ kn_) {
    const int row  = blockIdx.x * 4 + (threadIdx.x >> 6);  // [0, 32768)
    const int lane = threadIdx.x & 63;
    const int h = (row >> 10) & 15;
    const int n = row & (NN - 1);
    const float om = (lane < 32) ? omega[h * 32 + lane] : -omega[h * 32 + lane - 32];
    float sn, cs;
    sincosf((float)n * om, &sn, &cs);
    float* qrow = qp + (size_t)row * DD;
    float* krow = kp + (size_t)row * DD;
    const float qre = qrow[lane], qim = qrow[lane + 64];
    const float kre = krow[lane], kim = krow[lane + 64];
    float qs = fmaf(qre, qre, qim * qim);
    float ks = fmaf(kre, kre, kim * kim);
    qrow[lane]      = qre * cs - qim * sn;
    qrow[lane + 64] = qre * sn + qim * cs;
    krow[lane]      = kre * cs - kim * sn;
    krow[lane + 64] = kre * sn + kim * cs;
#pragma unroll
    for (int m2 = 1; m2 < 64; m2 <<= 1) {
        qs += __shfl_xor(qs, m2);
        ks += __shfl_xor(ks, m2);
    }
    if (lane == 0) { qn_[row] = qs; kn_[row] = ks; }
}

// ---------------------------------------------------------------------------
// Tiled flash attention. Block = 256 thr handles 64 query rows of one (b,h).
// grid (16, 32); i-tile index mirrored for second half of bh to balance the
// causal-triangle work across the 2-blocks-per-CU co-residency.
// S = Q128 @ K128^T via two 64-k halves through LDS; per-tile dt tables;
// online softmax; P routed through LDS (K buffer) into PV. Output -> qp alias.
// ---------------------------------------------------------------------------
__global__ __launch_bounds__(256) void attn_tiled(
    const float* __restrict__ qp, const float* __restrict__ kp,
    const float* __restrict__ vp,
    const float* __restrict__ qn, const float* __restrict__ kn,
    const float* __restrict__ mu_raw, const float* __restrict__ sigma_raw,
    const float* __restrict__ eta_raw, const float* __restrict__ gamma_raw,
    const float* __restrict__ tau_p, const float* __restrict__ nu_raw,
    float* __restrict__ y) {
    __shared__ float sA[64 * PADR];          // [kk][r] Q-half (transposed)
    __shared__ float sB[64 * PADR];          // [kk][c] K-half; then P[r][c]
    __shared__ float sV[64 * PADR];          // [c][d]  V-half (natural)
    __shared__ float sE[128], sIV[128], sBase[128];

    const int bh = blockIdx.y;
    const int b  = bh >> 4, h = bh & 15;
    const int it = (bh & 16) ? (15 - blockIdx.x) : blockIdx.x;
    const int i0 = it * 64;
    const int tid = threadIdx.x;
    const int tr = tid >> 4, tc = tid & 15;
    const int lr = tid & 63, lg = tid >> 6;  // loader: row, d-group

    const float mu     = 1.f / (1.f + expf(-mu_raw[h])) + 1e-4f;
    const float Ac     = log1pf(expf(sigma_raw[h])) / (2.f * mu);
    const float Cc     = log1pf(expf(eta_raw[h])) + log1pf(expf(gamma_raw[h]));
    const float nu     = log1pf(expf(nu_raw[h]));
    const float coef   = -0.5f * tau_p[h] * (nu + 64.0f);
    const float inv_nu = 1.f / nu;

    const float* Qb = qp + (size_t)bh * NN * DD;
    const float* Kb = kp + (size_t)bh * NN * DD;
    const float* Vb = vp + (size_t)bh * NN * DD;

    float mrow[4], lrow[4], O[4][8];
#pragma unroll
    for (int a = 0; a < 4; ++a) {
        mrow[a] = -INFINITY; lrow[a] = 0.f;
#pragma unroll
        for (int c = 0; c < 8; ++c) O[a][c] = 0.f;
    }
    float qnr[4];
#pragma unroll
    for (int a = 0; a < 4; ++a) qnr[a] = qn[(size_t)bh * NN + i0 + tr * 4 + a];

    for (int jt = 0; jt <= it; ++jt) {
        const int j0  = jt * 64;
        const int dt0 = i0 - j0;

        float acc[4][4];
#pragma unroll
        for (int a = 0; a < 4; ++a)
#pragma unroll
            for (int c = 0; c < 4; ++c) acc[a][c] = 0.f;

        // -------- S = sum over two 64-wide k-halves --------
#pragma unroll
        for (int half = 0; half < 2; ++half) {
#pragma unroll
            for (int s = 0; s < 4; ++s) {
                const int dl = lg * 16 + s * 4;
                float4 qv = *(const float4*)&Qb[(size_t)(i0 + lr) * DD + half * 64 + dl];
                float4 kv = *(const float4*)&Kb[(size_t)(j0 + lr) * DD + half * 64 + dl];
                sA[(dl + 0) * PADR + lr] = qv.x; sA[(dl + 1) * PADR + lr] = qv.y;
                sA[(dl + 2) * PADR + lr] = qv.z; sA[(dl + 3) * PADR + lr] = qv.w;
                sB[(dl + 0) * PADR + lr] = kv.x; sB[(dl + 1) * PADR + lr] = kv.y;
                sB[(dl + 2) * PADR + lr] = kv.z; sB[(dl + 3) * PADR + lr] = kv.w;
            }
            if (half == 0 && tid < 127) {    // per-tile dt tables, w = dt-dt0+63
                const int   dtv = dt0 + tid - 63;
                const float arg = fminf(fmaxf(-mu * (float)dtv, -30.f), 0.f);
                const float E   = expf(arg);
                const float V   = fmaf(Ac, 1.f - E * E, Cc);
                sE[tid] = E; sIV[tid] = 1.f / V; sBase[tid] = -32.f * logf(V);
            }
            __syncthreads();
#pragma unroll 4
            for (int kk = 0; kk < 64; ++kk) {
                float4 a4 = *(const float4*)&sA[kk * PADR + tr * 4];
                float4 b4 = *(const float4*)&sB[kk * PADR + tc * 4];
                acc[0][0] = fmaf(a4.x, b4.x, acc[0][0]); acc[0][1] = fmaf(a4.x, b4.y, acc[0][1]);
                acc[0][2] = fmaf(a4.x, b4.z, acc[0][2]); acc[0][3] = fmaf(a4.x, b4.w, acc[0][3]);
                acc[1][0] = fmaf(a4.y, b4.x, acc[1][0]); acc[1][1] = fmaf(a4.y, b4.y, acc[1][1]);
                acc[1][2] = fmaf(a4.y, b4.z, acc[1][2]); acc[1][3] = fmaf(a4.y, b4.w, acc[1][3]);
                acc[2][0] = fmaf(a4.z, b4.x, acc[2][0]); acc[2][1] = fmaf(a4.z, b4.y, acc[2][1]);
                acc[2][2] = fmaf(a4.z, b4.z, acc[2][2]); acc[2][3] = fmaf(a4.z, b4.w, acc[2][3]);
                acc[3][0] = fmaf(a4.w, b4.x, acc[3][0]); acc[3][1] = fmaf(a4.w, b4.y, acc[3][1]);
                acc[3][2] = fmaf(a4.w, b4.z, acc[3][2]); acc[3][3] = fmaf(a4.w, b4.w, acc[3][3]);
            }
            __syncthreads();
        }

        // per-column kn, prefetch V half 0
        float knc[4];
#pragma unroll
        for (int c = 0; c < 4; ++c) knc[c] = kn[(size_t)bh * NN + j0 + tc * 4 + c];
        float4 v0[4];
#pragma unroll
        for (int s = 0; s < 4; ++s)
            v0[s] = *(const float4*)&Vb[(size_t)(j0 + lr) * DD + lg * 16 + s * 4];

        // -------- softmax (logits -> P in-place in acc) --------
        float alpha[4];
#pragma unroll
        for (int a = 0; a < 4; ++a) {
            const int ra = tr * 4 + a;
            float rmax = -INFINITY;
#pragma unroll
            for (int c = 0; c < 4; ++c) {
                const int cc = tc * 4 + c;
                const int w  = ra - cc + 63;
                const float E    = sE[w];
                const float maha = fmaxf(fmaf(E * E, knc[c], qnr[a]) - 2.f * E * acc[a][c], 0.f) * sIV[w];
                float lgt = fmaf(coef, log1pf(maha * inv_nu), sBase[w]);
                if (dt0 + ra - cc < 0) lgt = -INFINITY;   // causal mask (diag tile)
                acc[a][c] = lgt;
                rmax = fmaxf(rmax, lgt);
            }
            rmax = fmaxf(rmax, __shfl_xor(rmax, 1));
            rmax = fmaxf(rmax, __shfl_xor(rmax, 2));
            rmax = fmaxf(rmax, __shfl_xor(rmax, 4));
            rmax = fmaxf(rmax, __shfl_xor(rmax, 8));
            const float mn = fmaxf(mrow[a], rmax);
            const float al = expf(mrow[a] - mn);
            float rsum = 0.f;
#pragma unroll
            for (int c = 0; c < 4; ++c) {
                const float p = expf(acc[a][c] - mn);
                acc[a][c] = p;
                rsum += p;
            }
            rsum += __shfl_xor(rsum, 1);
            rsum += __shfl_xor(rsum, 2);
            rsum += __shfl_xor(rsum, 4);
            rsum += __shfl_xor(rsum, 8);
            lrow[a] = fmaf(lrow[a], al, rsum);
            mrow[a] = mn;
            alpha[a] = al;
#pragma unroll
            for (int c = 0; c < 8; ++c) O[a][c] *= al;
        }

        // -------- P -> sB ; V0 -> sV ; prefetch V1 --------
#pragma unroll
        for (int a = 0; a < 4; ++a)
            *(float4*)&sB[(tr * 4 + a) * PADR + tc * 4] =
                make_float4(acc[a][0], acc[a][1], acc[a][2], acc[a][3]);
#pragma unroll
        for (int s = 0; s < 4; ++s)
            *(float4*)&sV[lr * PADR + lg * 16 + s * 4] = v0[s];
        float4 v1[4];
#pragma unroll
        for (int s = 0; s < 4; ++s)
            v1[s] = *(const float4*)&Vb[(size_t)(j0 + lr) * DD + 64 + lg * 16 + s * 4];
        __syncthreads();

        // -------- PV half 0 --------
#pragma unroll 4
        for (int kk = 0; kk < 64; ++kk) {
            float pa[4];
#pragma unroll
            for (int a = 0; a < 4; ++a) pa[a] = sB[(tr * 4 + a) * PADR + kk];
            float4 vv = *(const float4*)&sV[kk * PADR + tc * 4];
#pragma unroll
            for (int a = 0; a < 4; ++a) {
                O[a][0] = fmaf(pa[a], vv.x, O[a][0]);
                O[a][1] = fmaf(pa[a], vv.y, O[a][1]);
                O[a][2] = fmaf(pa[a], vv.z, O[a][2]);
                O[a][3] = fmaf(pa[a], vv.w, O[a][3]);
            }
        }
        __syncthreads();
#pragma unroll
        for (int s = 0; s < 4; ++s)
            *(float4*)&sV[lr * PADR + lg * 16 + s * 4] = v1[s];
        __syncthreads();

        // -------- PV half 1 --------
#pragma unroll 4
        for (int kk = 0; kk < 64; ++kk) {
            float pa[4];
#pragma unroll
            for (int a = 0; a < 4; ++a) pa[a] = sB[(tr * 4 + a) * PADR + kk];
            float4 vv = *(const float4*)&sV[kk * PADR + tc * 4];
#pragma unroll
            for (int a = 0; a < 4; ++a) {
                O[a][4] = fmaf(pa[a], vv.x, O[a][4]);
                O[a][5] = fmaf(pa[a], vv.y, O[a][5]);
                O[a][6] = fmaf(pa[a], vv.z, O[a][6]);
                O[a][7] = fmaf(pa[a], vv.w, O[a][7]);
            }
        }
        __syncthreads();
    }

    // -------- epilogue: O/l -> y (aliases qp; own rows only) --------
#pragma unroll
    for (int a = 0; a < 4; ++a) {
        const float inv = 1.f / lrow[a];
        const size_t rowo = ((size_t)bh * NN + i0 + tr * 4 + a) * DD;
        *(float4*)&y[rowo + tc * 4] =
            make_float4(O[a][0] * inv, O[a][1] * inv, O[a][2] * inv, O[a][3] * inv);
        *(float4*)&y[rowo + 64 + tc * 4] =
            make_float4(O[a][4] * inv, O[a][5] * inv, O[a][6] * inv, O[a][7] * inv);
    }
}

// ---------------------------------------------------------------------------
extern "C" void kernel_launch(void* const* d_in, const int* in_sizes, int n_in,
                              void* d_out, int out_size, void* d_ws, size_t ws_size,
                              hipStream_t stream) {
    const float* x         = (const float*)d_in[0];
    const float* Wq        = (const float*)d_in[1];
    const float* Wk        = (const float*)d_in[2];
    const float* Wv        = (const float*)d_in[3];
    const float* Wo        = (const float*)d_in[4];
    const float* omega     = (const float*)d_in[5];
    const float* mu_raw    = (const float*)d_in[6];
    const float* sigma_raw = (const float*)d_in[7];
    const float* eta_raw   = (const float*)d_in[8];
    const float* gamma_raw = (const float*)d_in[9];
    const float* tau       = (const float*)d_in[10];
    const float* nu_raw    = (const float*)d_in[11];
    float* out = (float*)d_out;

    // ws layout (floats): qp | kp | vp | qn | kn  (~50.6 MB)
    float* qp = (float*)d_ws;
    float* kp = qp + (size_t)BB * HH * NN * DD;
    float* vp = kp + (size_t)BB * HH * NN * DD;
    float* qn = vp + (size_t)BB * HH * NN * DD;
    float* kn = qn + (size_t)BB * HH * NN;

    gemm_qkv_pack<<<dim3(32, 32, 3), 256, 0, stream>>>(x, Wq, Wk, Wv, qp, kp, vp);
    rotate_qk<<<dim3(8192), 256, 0, stream>>>(qp, kp, omega, qn, kn);
    attn_tiled<<<dim3(16, 32), 256, 0, stream>>>(
        qp, kp, vp, qn, kn, mu_raw, sigma_raw, eta_raw, gamma_raw, tau, nu_raw, qp);
    gemm_out_remap<<<dim3(32, 16), 256, 0, stream>>>(qp, Wo, out);
}

// Round 3
// 476.445 us; speedup vs baseline: 11.7903x; 2.2667x over previous
//
#include <hip/hip_runtime.h>
#include <math.h>

// Problem constants (B=2, N=1024, DE=1024, H=16, DH=64 complex dims/head)
#define BB      2
#define NN      1024
#define DE_     1024
#define HH      16
#define TWO_DK  2048
#define DD      128         // per-head feature dim (re||im)
#define PADR    68          // LDS row stride (floats) for 64-wide attn tiles

typedef float f32x4  __attribute__((ext_vector_type(4)));
typedef short bf16x8 __attribute__((ext_vector_type(8)));

__device__ __forceinline__ short f2bf(float f) {
    unsigned u = __float_as_uint(f);
    unsigned r = (u + 0x7fffu + ((u >> 16) & 1u)) >> 16;   // RNE
    return (short)r;
}

#define GLDS16(g, l) __builtin_amdgcn_global_load_lds(                        \
    (const __attribute__((address_space(1))) unsigned int*)(g),               \
    (__attribute__((address_space(3))) unsigned int*)(l), 16, 0, 0)

// ---------------------------------------------------------------------------
// fp32 -> bf16 elementwise (x)
// ---------------------------------------------------------------------------
__global__ __launch_bounds__(256) void f32_to_bf16(
    const float* __restrict__ in, short* __restrict__ out, int n) {
    const int i = (blockIdx.x * 256 + threadIdx.x) * 4;
    if (i >= n) return;
    float4 v = *(const float4*)&in[i];
    short4 o; o.x = f2bf(v.x); o.y = f2bf(v.y); o.z = f2bf(v.z); o.w = f2bf(v.w);
    *(short4*)&out[i] = o;
}

// ---------------------------------------------------------------------------
// Transpose+convert W[K][N] fp32 -> Wt[N][K] bf16. z: 0..2 = Wq/Wk/Wv, 3 = Wo.
// ---------------------------------------------------------------------------
__global__ __launch_bounds__(256) void transpose_bf16(
    const float* __restrict__ Wq, const float* __restrict__ Wk,
    const float* __restrict__ Wv, const float* __restrict__ Wo,
    short* __restrict__ wt, short* __restrict__ wot) {
    const int z = blockIdx.z;
    const float* in; short* out; int R, C;
    if (z < 3) { in = (z == 0) ? Wq : (z == 1) ? Wk : Wv;
                 out = wt + (size_t)z * 2097152; R = 1024; C = 2048;
                 if (blockIdx.y >= 16) return; }
    else       { in = Wo; out = wot; R = 2048; C = 1024;
                 if (blockIdx.x >= 16) return; }
    __shared__ float t[64][65];
    const int c0 = blockIdx.x * 64, r0 = blockIdx.y * 64;
    const int tr = threadIdx.x >> 4, tc4 = (threadIdx.x & 15) * 4;
#pragma unroll
    for (int s = 0; s < 4; ++s) {
        const int r = tr + s * 16;
        float4 v = *(const float4*)&in[(size_t)(r0 + r) * C + c0 + tc4];
        t[r][tc4] = v.x; t[r][tc4 + 1] = v.y; t[r][tc4 + 2] = v.z; t[r][tc4 + 3] = v.w;
    }
    __syncthreads();
#pragma unroll
    for (int s = 0; s < 4; ++s) {
        const int oc = tr + s * 16;
        short4 o;
        o.x = f2bf(t[tc4 + 0][oc]); o.y = f2bf(t[tc4 + 1][oc]);
        o.z = f2bf(t[tc4 + 2][oc]); o.w = f2bf(t[tc4 + 3][oc]);
        *(short4*)&out[(size_t)(c0 + oc) * R + r0 + tc4] = o;
    }
}

// ---------------------------------------------------------------------------
// bf16 MFMA GEMM (m97 recipe): C[m][n] = sum_k A[m][k] * Bt[n][k].
// 128x128 tile, BK=64, 256 thr (4 waves, 2x2), 16x16x32 bf16 MFMA, XOR-swizzled
// LDS, global_load_lds width=16 staging.
// REMAP_A: A is packed y [(b*16+h)*1024+n][128] (re d<64, im d+64), m=b*1024+n,
//          k = im*1024 + h*64 + d (k0 64-aligned => (im,h) uniform per K-step).
// PACK_OUT: C written into packed q/k/v layout [(b*16+h)*1024+n][128].
// ---------------------------------------------------------------------------
template<int KDIM, int NDIM, bool REMAP_A, bool PACK_OUT>
__global__ __launch_bounds__(256) void gemm_mfma(
    const short* __restrict__ A, const short* __restrict__ Bt,
    float* __restrict__ Cb, size_t bStride, size_t cStride) {
    __shared__ __align__(16) short As[128 * 64];
    __shared__ __align__(16) short Bs[128 * 64];
    const int tid = threadIdx.x;
    const int m0  = blockIdx.x * 128;
    const int n0  = blockIdx.y * 128;
    const short* Bz = Bt + (size_t)blockIdx.z * bStride;
    float*       C  = Cb + (size_t)blockIdx.z * cStride;
    const int bb = m0 >> 10;

    int ldsoff[4], preA[4];
    const short* aP[4]; const short* bP[4];
#pragma unroll
    for (int i = 0; i < 4; ++i) {
        const int c   = i * 256 + tid;
        const int row = c >> 3;
        const int src = ((c & 7) ^ (row & 7)) << 3;   // XOR k-swizzle (elements)
        ldsoff[i] = c * 8;
        bP[i] = Bz + (size_t)(n0 + row) * KDIM + src;
        preA[i] = ((m0 & 1023) + row) * 128 + src;
        aP[i] = A + (size_t)(m0 + row) * KDIM + src;
    }

    const int lane = tid & 63, w = tid >> 6;
    const int wr = (w >> 1) * 64, wc = (w & 1) * 64;
    const int fr = lane & 15;
    const int fo = (lane >> 4) << 3;      // 0,8,16,24
    const int sw = (fr & 7) << 3;

    f32x4 acc[4][4];
#pragma unroll
    for (int a = 0; a < 4; ++a)
#pragma unroll
        for (int b = 0; b < 4; ++b) acc[a][b] = (f32x4){0.f, 0.f, 0.f, 0.f};

    for (int k0 = 0; k0 < KDIM; k0 += 64) {
#pragma unroll
        for (int i = 0; i < 4; ++i) {
            const short* ga;
            if (REMAP_A) {
                const int hh = (k0 >> 6) & 15, im = k0 >> 10;
                ga = A + ((size_t)(bb * 16 + hh) << 17) + im * 64 + preA[i];
            } else {
                ga = aP[i] + k0;
            }
            GLDS16(ga, &As[ldsoff[i]]);
        }
#pragma unroll
        for (int i = 0; i < 4; ++i) GLDS16(bP[i] + k0, &Bs[ldsoff[i]]);
        __syncthreads();    // drains vmcnt -> staged tiles visible
#pragma unroll
        for (int ks = 0; ks < 64; ks += 32) {
            bf16x8 af[4], bf[4];
#pragma unroll
            for (int a = 0; a < 4; ++a)
                af[a] = *(const bf16x8*)&As[(wr + a * 16 + fr) * 64 + ((ks + fo) ^ sw)];
#pragma unroll
            for (int b = 0; b < 4; ++b)
                bf[b] = *(const bf16x8*)&Bs[(wc + b * 16 + fr) * 64 + ((ks + fo) ^ sw)];
#pragma unroll
            for (int a = 0; a < 4; ++a)
#pragma unroll
                for (int b = 0; b < 4; ++b)
                    acc[a][b] = __builtin_amdgcn_mfma_f32_16x16x32_bf16(
                        af[a], bf[b], acc[a][b], 0, 0, 0);
        }
        __syncthreads();    // protect LDS before next stage
    }

    // epilogue: C/D layout col=lane&15, row=(lane>>4)*4+reg  [m89]
    const int cq = (lane >> 4) * 4, ccol = lane & 15;
#pragma unroll
    for (int a = 0; a < 4; ++a) {
        const int mr = m0 + wr + a * 16 + cq;
#pragma unroll
        for (int b = 0; b < 4; ++b) {
            const int col = n0 + wc + b * 16 + ccol;
#pragma unroll
            for (int r = 0; r < 4; ++r) {
                const int row = mr + r;
                if (PACK_OUT) {
                    const int im = col >> 10, hh = (col >> 6) & 15, d = col & 63;
                    const int b2 = row >> 10, n2 = row & 1023;
                    C[((size_t)(b2 * 16 + hh) * 1024 + n2) * 128 + im * 64 + d] = acc[a][b][r];
                } else {
                    C[(size_t)row * NDIM + col] = acc[a][b][r];
                }
            }
        }
    }
}

// ---------------------------------------------------------------------------
// In-place RoPE rotation of packed qp/kp rows + per-row squared norms.
// ---------------------------------------------------------------------------
__global__ __launch_bounds__(256) void rotate_qk(
    float* __restrict__ qp, float* __restrict__ kp,
    const float* __restrict__ omega,
    float* __restrict__ qn_, float* __restrict__ kn_) {
    const int row  = blockIdx.x * 4 + (threadIdx.x >> 6);
    const int lane = threadIdx.x & 63;
    const int h = (row >> 10) & 15;
    const int n = row & (NN - 1);
    const float om = (lane < 32) ? omega[h * 32 + lane] : -omega[h * 32 + lane - 32];
    float sn, cs;
    sincosf((float)n * om, &sn, &cs);
    float* qrow = qp + (size_t)row * DD;
    float* krow = kp + (size_t)row * DD;
    const float qre = qrow[lane], qim = qrow[lane + 64];
    const float kre = krow[lane], kim = krow[lane + 64];
    float qs = fmaf(qre, qre, qim * qim);
    float ks = fmaf(kre, kre, kim * kim);
    qrow[lane]      = qre * cs - qim * sn;
    qrow[lane + 64] = qre * sn + qim * cs;
    krow[lane]      = kre * cs - kim * sn;
    krow[lane + 64] = kre * sn + kim * cs;
#pragma unroll
    for (int m2 = 1; m2 < 64; m2 <<= 1) {
        qs += __shfl_xor(qs, m2);
        ks += __shfl_xor(ks, m2);
    }
    if (lane == 0) { qn_[row] = qs; kn_[row] = ks; }
}

// ---------------------------------------------------------------------------
// Tiled flash attention (unchanged structure from R2); epilogue now emits
// bf16 y in packed layout for the MFMA output GEMM.
// ---------------------------------------------------------------------------
__global__ __launch_bounds__(256) void attn_tiled(
    const float* __restrict__ qp, const float* __restrict__ kp,
    const float* __restrict__ vp,
    const float* __restrict__ qn, const float* __restrict__ kn,
    const float* __restrict__ mu_raw, const float* __restrict__ sigma_raw,
    const float* __restrict__ eta_raw, const float* __restrict__ gamma_raw,
    const float* __restrict__ tau_p, const float* __restrict__ nu_raw,
    short* __restrict__ y) {
    __shared__ float sA[64 * PADR];
    __shared__ float sB[64 * PADR];
    __shared__ float sV[64 * PADR];
    __shared__ float sE[128], sIV[128], sBase[128];

    const int bh = blockIdx.y;
    const int b  = bh >> 4, h = bh & 15;
    const int it = (bh & 16) ? (15 - blockIdx.x) : blockIdx.x;
    const int i0 = it * 64;
    const int tid = threadIdx.x;
    const int tr = tid >> 4, tc = tid & 15;
    const int lr = tid & 63, lg = tid >> 6;

    const float mu     = 1.f / (1.f + expf(-mu_raw[h])) + 1e-4f;
    const float Ac     = log1pf(expf(sigma_raw[h])) / (2.f * mu);
    const float Cc     = log1pf(expf(eta_raw[h])) + log1pf(expf(gamma_raw[h]));
    const float nu     = log1pf(expf(nu_raw[h]));
    const float coef   = -0.5f * tau_p[h] * (nu + 64.0f);
    const float inv_nu = 1.f / nu;

    const float* Qb = qp + (size_t)bh * NN * DD;
    const float* Kb = kp + (size_t)bh * NN * DD;
    const float* Vb = vp + (size_t)bh * NN * DD;

    float mrow[4], lrow[4], O[4][8];
#pragma unroll
    for (int a = 0; a < 4; ++a) {
        mrow[a] = -INFINITY; lrow[a] = 0.f;
#pragma unroll
        for (int c = 0; c < 8; ++c) O[a][c] = 0.f;
    }
    float qnr[4];
#pragma unroll
    for (int a = 0; a < 4; ++a) qnr[a] = qn[(size_t)bh * NN + i0 + tr * 4 + a];

    for (int jt = 0; jt <= it; ++jt) {
        const int j0  = jt * 64;
        const int dt0 = i0 - j0;

        float acc[4][4];
#pragma unroll
        for (int a = 0; a < 4; ++a)
#pragma unroll
            for (int c = 0; c < 4; ++c) acc[a][c] = 0.f;

#pragma unroll
        for (int half = 0; half < 2; ++half) {
#pragma unroll
            for (int s = 0; s < 4; ++s) {
                const int dl = lg * 16 + s * 4;
                float4 qv = *(const float4*)&Qb[(size_t)(i0 + lr) * DD + half * 64 + dl];
                float4 kv = *(const float4*)&Kb[(size_t)(j0 + lr) * DD + half * 64 + dl];
                sA[(dl + 0) * PADR + lr] = qv.x; sA[(dl + 1) * PADR + lr] = qv.y;
                sA[(dl + 2) * PADR + lr] = qv.z; sA[(dl + 3) * PADR + lr] = qv.w;
                sB[(dl + 0) * PADR + lr] = kv.x; sB[(dl + 1) * PADR + lr] = kv.y;
                sB[(dl + 2) * PADR + lr] = kv.z; sB[(dl + 3) * PADR + lr] = kv.w;
            }
            if (half == 0 && tid < 127) {
                const int   dtv = dt0 + tid - 63;
                const float arg = fminf(fmaxf(-mu * (float)dtv, -30.f), 0.f);
                const float E   = expf(arg);
                const float V   = fmaf(Ac, 1.f - E * E, Cc);
                sE[tid] = E; sIV[tid] = 1.f / V; sBase[tid] = -32.f * logf(V);
            }
            __syncthreads();
#pragma unroll 4
            for (int kk = 0; kk < 64; ++kk) {
                float4 a4 = *(const float4*)&sA[kk * PADR + tr * 4];
                float4 b4 = *(const float4*)&sB[kk * PADR + tc * 4];
                acc[0][0] = fmaf(a4.x, b4.x, acc[0][0]); acc[0][1] = fmaf(a4.x, b4.y, acc[0][1]);
                acc[0][2] = fmaf(a4.x, b4.z, acc[0][2]); acc[0][3] = fmaf(a4.x, b4.w, acc[0][3]);
                acc[1][0] = fmaf(a4.y, b4.x, acc[1][0]); acc[1][1] = fmaf(a4.y, b4.y, acc[1][1]);
                acc[1][2] = fmaf(a4.y, b4.z, acc[1][2]); acc[1][3] = fmaf(a4.y, b4.w, acc[1][3]);
                acc[2][0] = fmaf(a4.z, b4.x, acc[2][0]); acc[2][1] = fmaf(a4.z, b4.y, acc[2][1]);
                acc[2][2] = fmaf(a4.z, b4.z, acc[2][2]); acc[2][3] = fmaf(a4.z, b4.w, acc[2][3]);
                acc[3][0] = fmaf(a4.w, b4.x, acc[3][0]); acc[3][1] = fmaf(a4.w, b4.y, acc[3][1]);
                acc[3][2] = fmaf(a4.w, b4.z, acc[3][2]); acc[3][3] = fmaf(a4.w, b4.w, acc[3][3]);
            }
            __syncthreads();
        }

        float knc[4];
#pragma unroll
        for (int c = 0; c < 4; ++c) knc[c] = kn[(size_t)bh * NN + j0 + tc * 4 + c];
        float4 v0[4];
#pragma unroll
        for (int s = 0; s < 4; ++s)
            v0[s] = *(const float4*)&Vb[(size_t)(j0 + lr) * DD + lg * 16 + s * 4];

        float alpha[4];
#pragma unroll
        for (int a = 0; a < 4; ++a) {
            const int ra = tr * 4 + a;
            float rmax = -INFINITY;
#pragma unroll
            for (int c = 0; c < 4; ++c) {
                const int cc = tc * 4 + c;
                const int w2 = ra - cc + 63;
                const float E    = sE[w2];
                const float maha = fmaxf(fmaf(E * E, knc[c], qnr[a]) - 2.f * E * acc[a][c], 0.f) * sIV[w2];
                float lgt = fmaf(coef, log1pf(maha * inv_nu), sBase[w2]);
                if (dt0 + ra - cc < 0) lgt = -INFINITY;
                acc[a][c] = lgt;
                rmax = fmaxf(rmax, lgt);
            }
            rmax = fmaxf(rmax, __shfl_xor(rmax, 1));
            rmax = fmaxf(rmax, __shfl_xor(rmax, 2));
            rmax = fmaxf(rmax, __shfl_xor(rmax, 4));
            rmax = fmaxf(rmax, __shfl_xor(rmax, 8));
            const float mn = fmaxf(mrow[a], rmax);
            const float al = expf(mrow[a] - mn);
            float rsum = 0.f;
#pragma unroll
            for (int c = 0; c < 4; ++c) {
                const float p = expf(acc[a][c] - mn);
                acc[a][c] = p;
                rsum += p;
            }
            rsum += __shfl_xor(rsum, 1);
            rsum += __shfl_xor(rsum, 2);
            rsum += __shfl_xor(rsum, 4);
            rsum += __shfl_xor(rsum, 8);
            lrow[a] = fmaf(lrow[a], al, rsum);
            mrow[a] = mn;
            alpha[a] = al;
#pragma unroll
            for (int c = 0; c < 8; ++c) O[a][c] *= al;
        }

#pragma unroll
        for (int a = 0; a < 4; ++a)
            *(float4*)&sB[(tr * 4 + a) * PADR + tc * 4] =
                make_float4(acc[a][0], acc[a][1], acc[a][2], acc[a][3]);
#pragma unroll
        for (int s = 0; s < 4; ++s)
            *(float4*)&sV[lr * PADR + lg * 16 + s * 4] = v0[s];
        float4 v1[4];
#pragma unroll
        for (int s = 0; s < 4; ++s)
            v1[s] = *(const float4*)&Vb[(size_t)(j0 + lr) * DD + 64 + lg * 16 + s * 4];
        __syncthreads();

#pragma unroll 4
        for (int kk = 0; kk < 64; ++kk) {
            float pa[4];
#pragma unroll
            for (int a = 0; a < 4; ++a) pa[a] = sB[(tr * 4 + a) * PADR + kk];
            float4 vv = *(const float4*)&sV[kk * PADR + tc * 4];
#pragma unroll
            for (int a = 0; a < 4; ++a) {
                O[a][0] = fmaf(pa[a], vv.x, O[a][0]);
                O[a][1] = fmaf(pa[a], vv.y, O[a][1]);
                O[a][2] = fmaf(pa[a], vv.z, O[a][2]);
                O[a][3] = fmaf(pa[a], vv.w, O[a][3]);
            }
        }
        __syncthreads();
#pragma unroll
        for (int s = 0; s < 4; ++s)
            *(float4*)&sV[lr * PADR + lg * 16 + s * 4] = v1[s];
        __syncthreads();

#pragma unroll 4
        for (int kk = 0; kk < 64; ++kk) {
            float pa[4];
#pragma unroll
            for (int a = 0; a < 4; ++a) pa[a] = sB[(tr * 4 + a) * PADR + kk];
            float4 vv = *(const float4*)&sV[kk * PADR + tc * 4];
#pragma unroll
            for (int a = 0; a < 4; ++a) {
                O[a][4] = fmaf(pa[a], vv.x, O[a][4]);
                O[a][5] = fmaf(pa[a], vv.y, O[a][5]);
                O[a][6] = fmaf(pa[a], vv.z, O[a][6]);
                O[a][7] = fmaf(pa[a], vv.w, O[a][7]);
            }
        }
        __syncthreads();
    }

    // epilogue: O/l -> bf16 packed y
#pragma unroll
    for (int a = 0; a < 4; ++a) {
        const float inv = 1.f / lrow[a];
        const size_t rowo = ((size_t)bh * NN + i0 + tr * 4 + a) * DD;
        short4 lo, hi;
        lo.x = f2bf(O[a][0] * inv); lo.y = f2bf(O[a][1] * inv);
        lo.z = f2bf(O[a][2] * inv); lo.w = f2bf(O[a][3] * inv);
        hi.x = f2bf(O[a][4] * inv); hi.y = f2bf(O[a][5] * inv);
        hi.z = f2bf(O[a][6] * inv); hi.w = f2bf(O[a][7] * inv);
        *(short4*)&y[rowo + tc * 4] = lo;
        *(short4*)&y[rowo + 64 + tc * 4] = hi;
    }
}

// ---------------------------------------------------------------------------
extern "C" void kernel_launch(void* const* d_in, const int* in_sizes, int n_in,
                              void* d_out, int out_size, void* d_ws, size_t ws_size,
                              hipStream_t stream) {
    const float* x         = (const float*)d_in[0];
    const float* Wq        = (const float*)d_in[1];
    const float* Wk        = (const float*)d_in[2];
    const float* Wv        = (const float*)d_in[3];
    const float* Wo        = (const float*)d_in[4];
    const float* omega     = (const float*)d_in[5];
    const float* mu_raw    = (const float*)d_in[6];
    const float* sigma_raw = (const float*)d_in[7];
    const float* eta_raw   = (const float*)d_in[8];
    const float* gamma_raw = (const float*)d_in[9];
    const float* tau       = (const float*)d_in[10];
    const float* nu_raw    = (const float*)d_in[11];
    float* out = (float*)d_out;

    // ws layout: qkv fp32 (3x4.19M f) | qn,kn | wot bf16 | wt bf16 (x3) | xb bf16
    // yb (bf16, 4.19M elts) aliases wt (dead after gemm_qkv).   total ~71.6 MB
    const size_t PK = (size_t)BB * HH * NN * DD;   // 4,194,304
    float* qkv = (float*)d_ws;
    float* qp  = qkv;
    float* kp  = qkv + PK;
    float* vp  = qkv + 2 * PK;
    float* qn  = qkv + 3 * PK;
    float* kn  = qn + (size_t)BB * HH * NN;
    short* wot = (short*)(kn + (size_t)BB * HH * NN);
    short* wt  = wot + 2097152;
    short* xb  = wt + 3 * 2097152;
    short* yb  = wt;                                // alias

    f32_to_bf16<<<dim3(2048), 256, 0, stream>>>(x, xb, 2097152);
    transpose_bf16<<<dim3(32, 32, 4), 256, 0, stream>>>(Wq, Wk, Wv, Wo, wt, wot);
    gemm_mfma<1024, 2048, false, true><<<dim3(16, 16, 3), 256, 0, stream>>>(
        xb, wt, qkv, (size_t)2097152, PK);
    rotate_qk<<<dim3(8192), 256, 0, stream>>>(qp, kp, omega, qn, kn);
    attn_tiled<<<dim3(16, 32), 256, 0, stream>>>(
        qp, kp, vp, qn, kn, mu_raw, sigma_raw, eta_raw, gamma_raw, tau, nu_raw, yb);
    gemm_mfma<2048, 1024, true, false><<<dim3(16, 8, 1), 256, 0, stream>>>(
        yb, wot, out, 0, 0);
}

// Round 4
// 256.098 us; speedup vs baseline: 21.9347x; 1.8604x over previous
//
#include <hip/hip_runtime.h>
#include <math.h>

// Problem constants (B=2, N=1024, DE=1024, H=16, DH=64 complex dims/head)
#define BB      2
#define NN      1024
#define DE_     1024
#define HH      16
#define TWO_DK  2048
#define PK      4194304     // B*H*N*128 packed elements per q/k/v stream

typedef float f32x4  __attribute__((ext_vector_type(4)));
typedef short bf16x8 __attribute__((ext_vector_type(8)));

__device__ __forceinline__ short f2bf(float f) {
    unsigned u = __float_as_uint(f);
    unsigned r = (u + 0x7fffu + ((u >> 16) & 1u)) >> 16;   // RNE
    return (short)r;
}
__device__ __forceinline__ float bf2f(short s) {
    return __uint_as_float(((unsigned)(unsigned short)s) << 16);
}

#define GLDS16(g, l) __builtin_amdgcn_global_load_lds(                        \
    (const __attribute__((address_space(1))) unsigned int*)(g),               \
    (__attribute__((address_space(3))) unsigned int*)(l), 16, 0, 0)

// ---------------------------------------------------------------------------
// fp32 -> bf16 elementwise (x)
// ---------------------------------------------------------------------------
__global__ __launch_bounds__(256) void f32_to_bf16(
    const float* __restrict__ in, short* __restrict__ out, int n) {
    const int i = (blockIdx.x * 256 + threadIdx.x) * 4;
    if (i >= n) return;
    float4 v = *(const float4*)&in[i];
    short4 o; o.x = f2bf(v.x); o.y = f2bf(v.y); o.z = f2bf(v.z); o.w = f2bf(v.w);
    *(short4*)&out[i] = o;
}

// ---------------------------------------------------------------------------
// Transpose+convert W[K][N] fp32 -> Wt[N][K] bf16. z: 0..2 = Wq/Wk/Wv, 3 = Wo.
// ---------------------------------------------------------------------------
__global__ __launch_bounds__(256) void transpose_bf16(
    const float* __restrict__ Wq, const float* __restrict__ Wk,
    const float* __restrict__ Wv, const float* __restrict__ Wo,
    short* __restrict__ wt, short* __restrict__ wot) {
    const int z = blockIdx.z;
    const float* in; short* out; int R, C;
    if (z < 3) { in = (z == 0) ? Wq : (z == 1) ? Wk : Wv;
                 out = wt + (size_t)z * 2097152; R = 1024; C = 2048;
                 if (blockIdx.y >= 16) return; }
    else       { in = Wo; out = wot; R = 2048; C = 1024;
                 if (blockIdx.x >= 16) return; }
    __shared__ float t[64][65];
    const int c0 = blockIdx.x * 64, r0 = blockIdx.y * 64;
    const int tr = threadIdx.x >> 4, tc4 = (threadIdx.x & 15) * 4;
#pragma unroll
    for (int s = 0; s < 4; ++s) {
        const int r = tr + s * 16;
        float4 v = *(const float4*)&in[(size_t)(r0 + r) * C + c0 + tc4];
        t[r][tc4] = v.x; t[r][tc4 + 1] = v.y; t[r][tc4 + 2] = v.z; t[r][tc4 + 3] = v.w;
    }
    __syncthreads();
#pragma unroll
    for (int s = 0; s < 4; ++s) {
        const int oc = tr + s * 16;
        short4 o;
        o.x = f2bf(t[tc4 + 0][oc]); o.y = f2bf(t[tc4 + 1][oc]);
        o.z = f2bf(t[tc4 + 2][oc]); o.w = f2bf(t[tc4 + 3][oc]);
        *(short4*)&out[(size_t)(c0 + oc) * R + r0 + tc4] = o;
    }
}

// ---------------------------------------------------------------------------
// bf16 MFMA GEMM (m97 recipe): C = A * Bt^T. 128x128 tile, BK=64, 4 waves.
// OUTMODE 0: plain f32 C[row*NDIM+col].
// OUTMODE 1 (qkv): z<2 -> bf16 packed q/k [(b*16+h)*1024+n][128];
//                  z==2 -> bf16 transposed V: vt[(b*16+h)*128 + dd][n].
// REMAP_A: A is packed y [(b*16+h)*1024+n][128], k = im*1024 + h*64 + d.
// ---------------------------------------------------------------------------
template<int KDIM, int NDIM, bool REMAP_A, int OUTMODE>
__global__ __launch_bounds__(256) void gemm_mfma(
    const short* __restrict__ A, const short* __restrict__ Bt,
    float* __restrict__ Cf, short* __restrict__ Cqk, short* __restrict__ Cvt,
    size_t bStride) {
    __shared__ __align__(16) short As[128 * 64];
    __shared__ __align__(16) short Bs[128 * 64];
    const int tid = threadIdx.x;
    const int m0  = blockIdx.x * 128;
    const int n0  = blockIdx.y * 128;
    const short* Bz = Bt + (size_t)blockIdx.z * bStride;
    const int bb = m0 >> 10;

    int ldsoff[4], preA[4];
    const short* aP[4]; const short* bP[4];
#pragma unroll
    for (int i = 0; i < 4; ++i) {
        const int c   = i * 256 + tid;
        const int row = c >> 3;
        const int src = ((c & 7) ^ (row & 7)) << 3;   // XOR k-swizzle (elements)
        ldsoff[i] = c * 8;
        bP[i] = Bz + (size_t)(n0 + row) * KDIM + src;
        preA[i] = ((m0 & 1023) + row) * 128 + src;
        aP[i] = A + (size_t)(m0 + row) * KDIM + src;
    }

    const int lane = tid & 63, w = tid >> 6;
    const int wr = (w >> 1) * 64, wc = (w & 1) * 64;
    const int fr = lane & 15;
    const int fo = (lane >> 4) << 3;
    const int sw = (fr & 7) << 3;

    f32x4 acc[4][4];
#pragma unroll
    for (int a = 0; a < 4; ++a)
#pragma unroll
        for (int b = 0; b < 4; ++b) acc[a][b] = (f32x4){0.f, 0.f, 0.f, 0.f};

    for (int k0 = 0; k0 < KDIM; k0 += 64) {
#pragma unroll
        for (int i = 0; i < 4; ++i) {
            const short* ga;
            if (REMAP_A) {
                const int hh = (k0 >> 6) & 15, im = k0 >> 10;
                ga = A + ((size_t)(bb * 16 + hh) << 17) + im * 64 + preA[i];
            } else {
                ga = aP[i] + k0;
            }
            GLDS16(ga, &As[ldsoff[i]]);
        }
#pragma unroll
        for (int i = 0; i < 4; ++i) GLDS16(bP[i] + k0, &Bs[ldsoff[i]]);
        __syncthreads();
#pragma unroll
        for (int ks = 0; ks < 64; ks += 32) {
            bf16x8 af[4], bf[4];
#pragma unroll
            for (int a = 0; a < 4; ++a)
                af[a] = *(const bf16x8*)&As[(wr + a * 16 + fr) * 64 + ((ks + fo) ^ sw)];
#pragma unroll
            for (int b = 0; b < 4; ++b)
                bf[b] = *(const bf16x8*)&Bs[(wc + b * 16 + fr) * 64 + ((ks + fo) ^ sw)];
#pragma unroll
            for (int a = 0; a < 4; ++a)
#pragma unroll
                for (int b = 0; b < 4; ++b)
                    acc[a][b] = __builtin_amdgcn_mfma_f32_16x16x32_bf16(
                        af[a], bf[b], acc[a][b], 0, 0, 0);
        }
        __syncthreads();
    }

    // epilogue: C/D layout col=lane&15, row=(lane>>4)*4+reg  [m89]
    const int cq = (lane >> 4) * 4, ccol = lane & 15;
#pragma unroll
    for (int a = 0; a < 4; ++a) {
        const int mr = m0 + wr + a * 16 + cq;
#pragma unroll
        for (int b = 0; b < 4; ++b) {
            const int col = n0 + wc + b * 16 + ccol;
#pragma unroll
            for (int r = 0; r < 4; ++r) {
                const int row = mr + r;
                const float val = acc[a][b][r];
                if (OUTMODE == 0) {
                    Cf[(size_t)row * NDIM + col] = val;
                } else {
                    const int im = col >> 10, hh = (col >> 6) & 15, d = col & 63;
                    const int dd = im * 64 + d;
                    const int b2 = row >> 10, n2 = row & 1023;
                    if (blockIdx.z < 2)
                        Cqk[(size_t)blockIdx.z * PK +
                            ((size_t)(b2 * 16 + hh) * 1024 + n2) * 128 + dd] = f2bf(val);
                    else
                        Cvt[((size_t)(b2 * 16 + hh) * 128 + dd) * 1024 + n2] = f2bf(val);
                }
            }
        }
    }
}

// ---------------------------------------------------------------------------
// In-place RoPE rotation of packed bf16 q/k rows + per-row squared norms.
// One wave per row (lane = complex dim d).
// ---------------------------------------------------------------------------
__global__ __launch_bounds__(256) void rotate_qk(
    short* __restrict__ qb, short* __restrict__ kb,
    const float* __restrict__ omega,
    float* __restrict__ qn_, float* __restrict__ kn_) {
    const int row  = blockIdx.x * 4 + (threadIdx.x >> 6);
    const int lane = threadIdx.x & 63;
    const int h = (row >> 10) & 15;
    const int n = row & (NN - 1);
    const float om = (lane < 32) ? omega[h * 32 + lane] : -omega[h * 32 + lane - 32];
    float sn, cs;
    sincosf((float)n * om, &sn, &cs);
    short* qrow = qb + (size_t)row * 128;
    short* krow = kb + (size_t)row * 128;
    const float qre = bf2f(qrow[lane]), qim = bf2f(qrow[lane + 64]);
    const float kre = bf2f(krow[lane]), kim = bf2f(krow[lane + 64]);
    float qs = fmaf(qre, qre, qim * qim);
    float ks = fmaf(kre, kre, kim * kim);
    qrow[lane]      = f2bf(qre * cs - qim * sn);
    qrow[lane + 64] = f2bf(qre * sn + qim * cs);
    krow[lane]      = f2bf(kre * cs - kim * sn);
    krow[lane + 64] = f2bf(kre * sn + kim * cs);
#pragma unroll
    for (int m2 = 1; m2 < 64; m2 <<= 1) {
        qs += __shfl_xor(qs, m2);
        ks += __shfl_xor(ks, m2);
    }
    if (lane == 0) { qn_[row] = qs; kn_[row] = ks; }
}

// ---------------------------------------------------------------------------
// MFMA flash attention. Block = 256 thr = 4 waves, 64 Q-rows of one (b,h).
// Wave w owns rows w*16..w*16+15 (all 64 cols / 128 d).
// S = Q@K^T and O += P@V via 16x16x32 bf16 MFMA; softmax on C-layout regs;
// P routed through LDS (bf16); dt tables (E,1/V,-32logV) as float4 in LDS.
// ---------------------------------------------------------------------------
__global__ __launch_bounds__(256) void attn_mfma(
    const short* __restrict__ qr, const short* __restrict__ kr,
    const short* __restrict__ vt,
    const float* __restrict__ qn, const float* __restrict__ kn,
    const float* __restrict__ mu_raw, const float* __restrict__ sigma_raw,
    const float* __restrict__ eta_raw, const float* __restrict__ gamma_raw,
    const float* __restrict__ tau_p, const float* __restrict__ nu_raw,
    short* __restrict__ y) {
    __shared__ __align__(16) short Qs[64 * 128];   // [row][k], 16B-chunk XOR swizzle
    __shared__ __align__(16) short Ks[64 * 128];
    __shared__ __align__(16) short Vs[128 * 64];   // [d][j],   16B-chunk XOR swizzle
    __shared__ __align__(16) short Ps[64 * 72];    // [row][col], pad 72
    __shared__ float4 sT[128];                     // (E, 1/V, -32logV, 0) by idx=dt-dt0+63
    __shared__ float  sKn[64];

    const int bh = blockIdx.y;
    const int h  = bh & 15;
    const int it = (bh & 16) ? (15 - (int)blockIdx.x) : (int)blockIdx.x;
    const int i0 = it * 64;
    const int tid  = threadIdx.x;
    const int lane = tid & 63, w = tid >> 6;
    const int quad = lane >> 4, l15 = lane & 15;

    const float mu     = 1.f / (1.f + expf(-mu_raw[h])) + 1e-4f;
    const float Ac     = log1pf(expf(sigma_raw[h])) / (2.f * mu);
    const float Cc     = log1pf(expf(eta_raw[h])) + log1pf(expf(gamma_raw[h]));
    const float nu     = log1pf(expf(nu_raw[h]));
    const float coef   = -0.5f * tau_p[h] * (nu + 64.0f);
    const float inv_nu = 1.f / nu;

    const short* Qb  = qr + (size_t)bh * NN * 128;
    const short* Kb  = kr + (size_t)bh * NN * 128;
    const short* Vtb = vt + (size_t)bh * 128 * NN;

    // stage Q once (persists across jt loop)
#pragma unroll
    for (int i = 0; i < 4; ++i) {
        const int c = i * 256 + tid, row = c >> 4, src = ((c & 15) ^ (row & 7)) * 8;
        GLDS16(Qb + (size_t)(i0 + row) * 128 + src, &Qs[c * 8]);
    }

    float mrow[4], lrow[4];
    f32x4 o[8];
#pragma unroll
    for (int r = 0; r < 4; ++r) { mrow[r] = -INFINITY; lrow[r] = 0.f; }
#pragma unroll
    for (int s = 0; s < 8; ++s) o[s] = (f32x4){0.f, 0.f, 0.f, 0.f};
    float qn4[4];
#pragma unroll
    for (int r = 0; r < 4; ++r)
        qn4[r] = qn[(size_t)bh * NN + i0 + w * 16 + quad * 4 + r];

    for (int jt = 0; jt <= it; ++jt) {
        const int j0 = jt * 64, dt0 = i0 - j0;
        // stage K tile [64 rows][128 k]
#pragma unroll
        for (int i = 0; i < 4; ++i) {
            const int c = i * 256 + tid, row = c >> 4, src = ((c & 15) ^ (row & 7)) * 8;
            GLDS16(Kb + (size_t)(j0 + row) * 128 + src, &Ks[c * 8]);
        }
        // stage V tile [128 d][64 j]
#pragma unroll
        for (int i = 0; i < 4; ++i) {
            const int c = i * 256 + tid, d = c >> 3, src = ((c & 7) ^ (d & 7)) * 8;
            GLDS16(Vtb + (size_t)d * NN + j0 + src, &Vs[c * 8]);
        }
        // dt tables + column norms
        if (tid < 128) {
            const int   dtv = dt0 + tid - 63;
            const float arg = fminf(fmaxf(-mu * (float)dtv, -30.f), 0.f);
            const float E   = expf(arg);
            const float V   = fmaf(Ac, 1.f - E * E, Cc);
            sT[tid] = make_float4(E, 1.f / V, -32.f * logf(V), 0.f);
        } else if (tid < 192) {
            sKn[tid - 128] = kn[(size_t)bh * NN + j0 + tid - 128];
        }
        __syncthreads();

        // -------- S = Q @ K^T (this wave: rows w*16.., all 64 cols) --------
        f32x4 sAcc[4];
#pragma unroll
        for (int s = 0; s < 4; ++s) sAcc[s] = (f32x4){0.f, 0.f, 0.f, 0.f};
        const int arow = w * 16 + l15;
#pragma unroll
        for (int ks = 0; ks < 4; ++ks) {
            bf16x8 aQ = *(const bf16x8*)&Qs[arow * 128 + (((ks * 4 + quad) ^ (arow & 7)) * 8)];
#pragma unroll
            for (int s = 0; s < 4; ++s) {
                const int brow = s * 16 + l15;
                bf16x8 bK = *(const bf16x8*)&Ks[brow * 128 + (((ks * 4 + quad) ^ (brow & 7)) * 8)];
                sAcc[s] = __builtin_amdgcn_mfma_f32_16x16x32_bf16(aQ, bK, sAcc[s], 0, 0, 0);
            }
        }

        // -------- softmax on C-layout (row = w*16+quad*4+r, col = s*16+l15) --------
        float al[4];
#pragma unroll
        for (int r = 0; r < 4; ++r) {
            const int row = w * 16 + quad * 4 + r;
            float lg[4];
            float mx = -INFINITY;
#pragma unroll
            for (int s = 0; s < 4; ++s) {
                const int col = s * 16 + l15;
                const float4 T = sT[row - col + 63];
                const float sv = sAcc[s][r];
                const float maha =
                    fmaxf(fmaf(T.x * T.x, sKn[col], qn4[r]) - 2.f * T.x * sv, 0.f) * T.y;
                float v = fmaf(coef, __logf(fmaf(maha, inv_nu, 1.f)), T.z);
                if (jt == it && col > row) v = -INFINITY;
                lg[s] = v;
                mx = fmaxf(mx, v);
            }
            mx = fmaxf(mx, __shfl_xor(mx, 1));
            mx = fmaxf(mx, __shfl_xor(mx, 2));
            mx = fmaxf(mx, __shfl_xor(mx, 4));
            mx = fmaxf(mx, __shfl_xor(mx, 8));
            const float mn = fmaxf(mrow[r], mx);
            const float a_ = __expf(mrow[r] - mn);
            float rs = 0.f;
#pragma unroll
            for (int s = 0; s < 4; ++s) {
                const float p = __expf(lg[s] - mn);
                Ps[row * 72 + s * 16 + l15] = f2bf(p);
                rs += p;
            }
            rs += __shfl_xor(rs, 1);
            rs += __shfl_xor(rs, 2);
            rs += __shfl_xor(rs, 4);
            rs += __shfl_xor(rs, 8);
            lrow[r] = fmaf(lrow[r], a_, rs);
            mrow[r] = mn;
            al[r] = a_;
        }
        // rescale O
#pragma unroll
        for (int s = 0; s < 8; ++s)
#pragma unroll
            for (int r = 0; r < 4; ++r) o[s][r] *= al[r];

        // -------- O += P @ V (P rows own-wave only: no barrier needed) --------
#pragma unroll
        for (int jc = 0; jc < 2; ++jc) {
            bf16x8 aP = *(const bf16x8*)&Ps[(w * 16 + l15) * 72 + jc * 32 + quad * 8];
#pragma unroll
            for (int sub = 0; sub < 8; ++sub) {
                const int d = sub * 16 + l15;
                bf16x8 bV = *(const bf16x8*)&Vs[d * 64 + (((jc * 4 + quad) ^ (d & 7)) * 8)];
                o[sub] = __builtin_amdgcn_mfma_f32_16x16x32_bf16(aP, bV, o[sub], 0, 0, 0);
            }
        }
        __syncthreads();   // protect Ks/Vs/sT before next tile's staging
    }

    // -------- epilogue: O/l -> bf16 packed y --------
#pragma unroll
    for (int r = 0; r < 4; ++r) {
        const float inv = 1.f / lrow[r];
        const size_t base = ((size_t)bh * NN + i0 + w * 16 + quad * 4 + r) * 128;
#pragma unroll
        for (int sub = 0; sub < 8; ++sub)
            y[base + sub * 16 + l15] = f2bf(o[sub][r] * inv);
    }
}

// ---------------------------------------------------------------------------
extern "C" void kernel_launch(void* const* d_in, const int* in_sizes, int n_in,
                              void* d_out, int out_size, void* d_ws, size_t ws_size,
                              hipStream_t stream) {
    const float* x         = (const float*)d_in[0];
    const float* Wq        = (const float*)d_in[1];
    const float* Wk        = (const float*)d_in[2];
    const float* Wv        = (const float*)d_in[3];
    const float* Wo        = (const float*)d_in[4];
    const float* omega     = (const float*)d_in[5];
    const float* mu_raw    = (const float*)d_in[6];
    const float* sigma_raw = (const float*)d_in[7];
    const float* eta_raw   = (const float*)d_in[8];
    const float* gamma_raw = (const float*)d_in[9];
    const float* tau       = (const float*)d_in[10];
    const float* nu_raw    = (const float*)d_in[11];
    float* out = (float*)d_out;

    // ws (bf16/f32 mixed, ~50.6 MB):
    // qb | kb | vtb (bf16, PK each) | qn | kn (f32) | wot | wt x3 | xb (bf16)
    // yb aliases wt (dead after qkv GEMM).
    short* qb  = (short*)d_ws;
    short* kb  = qb + PK;
    short* vtb = kb + PK;
    float* qn  = (float*)(vtb + PK);
    float* kn  = qn + 32768;
    short* wot = (short*)(kn + 32768);
    short* wt  = wot + 2097152;
    short* xb  = wt + 3 * 2097152;
    short* yb  = wt;                               // alias

    f32_to_bf16<<<dim3(2048), 256, 0, stream>>>(x, xb, 2097152);
    transpose_bf16<<<dim3(32, 32, 4), 256, 0, stream>>>(Wq, Wk, Wv, Wo, wt, wot);
    gemm_mfma<1024, 2048, false, 1><<<dim3(16, 16, 3), 256, 0, stream>>>(
        xb, wt, nullptr, qb, vtb, (size_t)2097152);
    rotate_qk<<<dim3(8192), 256, 0, stream>>>(qb, kb, omega, qn, kn);
    attn_mfma<<<dim3(16, 32), 256, 0, stream>>>(
        qb, kb, vtb, qn, kn, mu_raw, sigma_raw, eta_raw, gamma_raw, tau, nu_raw, yb);
    gemm_mfma<2048, 1024, true, 0><<<dim3(16, 8, 1), 256, 0, stream>>>(
        yb, wot, out, nullptr, nullptr, 0);
}

// Round 5
// 247.841 us; speedup vs baseline: 22.6655x; 1.0333x over previous
//
#include <hip/hip_runtime.h>
#include <math.h>

// Problem constants (B=2, N=1024, DE=1024, H=16, DH=64 complex dims/head)
#define BB      2
#define NN      1024
#define DE_     1024
#define HH      16
#define TWO_DK  2048
#define PK      4194304     // B*H*N*128 packed elements per q/k/v stream
#define TBLR    1092        // per-head table entries: dt in [-64, 1028)

typedef float f32x4  __attribute__((ext_vector_type(4)));
typedef short bf16x8 __attribute__((ext_vector_type(8)));

__device__ __forceinline__ short f2bf(float f) {
    unsigned u = __float_as_uint(f);
    unsigned r = (u + 0x7fffu + ((u >> 16) & 1u)) >> 16;   // RNE
    return (short)r;
}
__device__ __forceinline__ float bf2f(short s) {
    return __uint_as_float(((unsigned)(unsigned short)s) << 16);
}

#define GLDS16(g, l) __builtin_amdgcn_global_load_lds(                        \
    (const __attribute__((address_space(1))) unsigned int*)(g),               \
    (__attribute__((address_space(3))) unsigned int*)(l), 16, 0, 0)
#define GLDS4(g, l) __builtin_amdgcn_global_load_lds(                         \
    (const __attribute__((address_space(1))) unsigned int*)(g),               \
    (__attribute__((address_space(3))) unsigned int*)(l), 4, 0, 0)

// ---------------------------------------------------------------------------
// fp32 -> bf16 elementwise (x)
// ---------------------------------------------------------------------------
__global__ __launch_bounds__(256) void f32_to_bf16(
    const float* __restrict__ in, short* __restrict__ out, int n) {
    const int i = (blockIdx.x * 256 + threadIdx.x) * 4;
    if (i >= n) return;
    float4 v = *(const float4*)&in[i];
    short4 o; o.x = f2bf(v.x); o.y = f2bf(v.y); o.z = f2bf(v.z); o.w = f2bf(v.w);
    *(short4*)&out[i] = o;
}

// ---------------------------------------------------------------------------
// Transpose+convert W[K][N] fp32 -> Wt[N][K] bf16. z: 0..2 = Wq/Wk/Wv, 3 = Wo.
// ---------------------------------------------------------------------------
__global__ __launch_bounds__(256) void transpose_bf16(
    const float* __restrict__ Wq, const float* __restrict__ Wk,
    const float* __restrict__ Wv, const float* __restrict__ Wo,
    short* __restrict__ wt, short* __restrict__ wot) {
    const int z = blockIdx.z;
    const float* in; short* out; int R, C;
    if (z < 3) { in = (z == 0) ? Wq : (z == 1) ? Wk : Wv;
                 out = wt + (size_t)z * 2097152; R = 1024; C = 2048;
                 if (blockIdx.y >= 16) return; }
    else       { in = Wo; out = wot; R = 2048; C = 1024;
                 if (blockIdx.x >= 16) return; }
    __shared__ float t[64][65];
    const int c0 = blockIdx.x * 64, r0 = blockIdx.y * 64;
    const int tr = threadIdx.x >> 4, tc4 = (threadIdx.x & 15) * 4;
#pragma unroll
    for (int s = 0; s < 4; ++s) {
        const int r = tr + s * 16;
        float4 v = *(const float4*)&in[(size_t)(r0 + r) * C + c0 + tc4];
        t[r][tc4] = v.x; t[r][tc4 + 1] = v.y; t[r][tc4 + 2] = v.z; t[r][tc4 + 3] = v.w;
    }
    __syncthreads();
#pragma unroll
    for (int s = 0; s < 4; ++s) {
        const int oc = tr + s * 16;
        short4 o;
        o.x = f2bf(t[tc4 + 0][oc]); o.y = f2bf(t[tc4 + 1][oc]);
        o.z = f2bf(t[tc4 + 2][oc]); o.w = f2bf(t[tc4 + 3][oc]);
        *(short4*)&out[(size_t)(c0 + oc) * R + r0 + tc4] = o;
    }
}

// ---------------------------------------------------------------------------
// Per-(h, dt) decay tables: (E, 1/V, -32*logV, 0). dt = r - 64, r in [0,1092).
// ---------------------------------------------------------------------------
__global__ __launch_bounds__(256) void tbl_precomp(
    const float* __restrict__ mu_raw, const float* __restrict__ sigma_raw,
    const float* __restrict__ eta_raw, const float* __restrict__ gamma_raw,
    float4* __restrict__ tbl) {
    const int h = blockIdx.y;
    const int r = blockIdx.x * 256 + threadIdx.x;
    if (r >= TBLR) return;
    const float mu = 1.f / (1.f + expf(-mu_raw[h])) + 1e-4f;
    const float Ac = log1pf(expf(sigma_raw[h])) / (2.f * mu);
    const float Cc = log1pf(expf(eta_raw[h])) + log1pf(expf(gamma_raw[h]));
    const int   dt = r - 64;
    const float arg = fminf(fmaxf(-mu * (float)dt, -30.f), 0.f);
    const float E   = expf(arg);
    const float V   = fmaf(Ac, 1.f - E * E, Cc);
    tbl[h * TBLR + r] = make_float4(E, 1.f / V, -32.f * logf(V), 0.f);
}

// ---------------------------------------------------------------------------
// bf16 MFMA GEMM (m97 recipe): C = A * Bt^T. 128x128 tile, BK=64, 4 waves.
// OUTMODE 0: plain f32 store.
// OUTMODE 1 (qkv): z<2 -> bf16 packed q/k [(b*16+h)*1024+n][128];
//                  z==2 -> bf16 transposed V via 8B short4: vt[bh*128+dd][n].
// OUTMODE 2: f32 atomicAdd, K split 4-ways over blockIdx.z.
// REMAP_A: A is packed y [(b*16+h)*1024+n][128], k = im*1024 + h*64 + d.
// ---------------------------------------------------------------------------
template<int KDIM, int NDIM, bool REMAP_A, int OUTMODE>
__global__ __launch_bounds__(256) void gemm_mfma(
    const short* __restrict__ A, const short* __restrict__ Bt,
    float* __restrict__ Cf, short* __restrict__ Cqk, short* __restrict__ Cvt,
    size_t bStride) {
    __shared__ __align__(16) short As[128 * 64];
    __shared__ __align__(16) short Bs[128 * 64];
    const int tid = threadIdx.x;
    const int m0  = blockIdx.x * 128;
    const int n0  = blockIdx.y * 128;
    const short* Bz = (OUTMODE == 1) ? Bt + (size_t)blockIdx.z * bStride : Bt;
    const int bb = m0 >> 10;
    const int kBeg = (OUTMODE == 2) ? (int)blockIdx.z * (KDIM / 4) : 0;
    const int kEnd = (OUTMODE == 2) ? kBeg + KDIM / 4 : KDIM;

    int ldsoff[4], preA[4];
    const short* aP[4]; const short* bP[4];
#pragma unroll
    for (int i = 0; i < 4; ++i) {
        const int c   = i * 256 + tid;
        const int row = c >> 3;
        const int src = ((c & 7) ^ (row & 7)) << 3;   // XOR k-swizzle (elements)
        ldsoff[i] = c * 8;
        bP[i] = Bz + (size_t)(n0 + row) * KDIM + src;
        preA[i] = ((m0 & 1023) + row) * 128 + src;
        aP[i] = A + (size_t)(m0 + row) * KDIM + src;
    }

    const int lane = tid & 63, w = tid >> 6;
    const int wr = (w >> 1) * 64, wc = (w & 1) * 64;
    const int fr = lane & 15;
    const int fo = (lane >> 4) << 3;
    const int sw = (fr & 7) << 3;

    f32x4 acc[4][4];
#pragma unroll
    for (int a = 0; a < 4; ++a)
#pragma unroll
        for (int b = 0; b < 4; ++b) acc[a][b] = (f32x4){0.f, 0.f, 0.f, 0.f};

    for (int k0 = kBeg; k0 < kEnd; k0 += 64) {
#pragma unroll
        for (int i = 0; i < 4; ++i) {
            const short* ga;
            if (REMAP_A) {
                const int hh = (k0 >> 6) & 15, im = k0 >> 10;
                ga = A + ((size_t)(bb * 16 + hh) << 17) + im * 64 + preA[i];
            } else {
                ga = aP[i] + k0;
            }
            GLDS16(ga, &As[ldsoff[i]]);
        }
#pragma unroll
        for (int i = 0; i < 4; ++i) GLDS16(bP[i] + k0, &Bs[ldsoff[i]]);
        __syncthreads();
#pragma unroll
        for (int ks = 0; ks < 64; ks += 32) {
            bf16x8 af[4], bf[4];
#pragma unroll
            for (int a = 0; a < 4; ++a)
                af[a] = *(const bf16x8*)&As[(wr + a * 16 + fr) * 64 + ((ks + fo) ^ sw)];
#pragma unroll
            for (int b = 0; b < 4; ++b)
                bf[b] = *(const bf16x8*)&Bs[(wc + b * 16 + fr) * 64 + ((ks + fo) ^ sw)];
#pragma unroll
            for (int a = 0; a < 4; ++a)
#pragma unroll
                for (int b = 0; b < 4; ++b)
                    acc[a][b] = __builtin_amdgcn_mfma_f32_16x16x32_bf16(
                        af[a], bf[b], acc[a][b], 0, 0, 0);
        }
        __syncthreads();
    }

    // epilogue: C/D layout col=lane&15, row=(lane>>4)*4+reg  [m89]
    const int cq = (lane >> 4) * 4, ccol = lane & 15;
#pragma unroll
    for (int a = 0; a < 4; ++a) {
        const int mr = m0 + wr + a * 16 + cq;
#pragma unroll
        for (int b = 0; b < 4; ++b) {
            const int col = n0 + wc + b * 16 + ccol;
            if (OUTMODE == 1 && blockIdx.z == 2) {
                // V transposed: 4 rows are n-consecutive -> one 8B store
                const int im = col >> 10, hh = (col >> 6) & 15, d = col & 63;
                const int b2 = mr >> 10, n2 = mr & 1023;
                short4 o;
                o.x = f2bf(acc[a][b][0]); o.y = f2bf(acc[a][b][1]);
                o.z = f2bf(acc[a][b][2]); o.w = f2bf(acc[a][b][3]);
                *(short4*)&Cvt[((size_t)(b2 * 16 + hh) * 128 + im * 64 + d) * 1024 + n2] = o;
            } else {
#pragma unroll
                for (int r = 0; r < 4; ++r) {
                    const int row = mr + r;
                    const float val = acc[a][b][r];
                    if (OUTMODE == 0) {
                        Cf[(size_t)row * NDIM + col] = val;
                    } else if (OUTMODE == 2) {
                        atomicAdd(&Cf[(size_t)row * NDIM + col], val);
                    } else {
                        const int im = col >> 10, hh = (col >> 6) & 15, d = col & 63;
                        const int b2 = row >> 10, n2 = row & 1023;
                        Cqk[(size_t)blockIdx.z * PK +
                            ((size_t)(b2 * 16 + hh) * 1024 + n2) * 128 + im * 64 + d] =
                            f2bf(val);
                    }
                }
            }
        }
    }
}

// ---------------------------------------------------------------------------
// In-place RoPE rotation of packed bf16 q/k rows + per-row squared norms.
// ---------------------------------------------------------------------------
__global__ __launch_bounds__(256) void rotate_qk(
    short* __restrict__ qb, short* __restrict__ kb,
    const float* __restrict__ omega,
    float* __restrict__ qn_, float* __restrict__ kn_) {
    const int row  = blockIdx.x * 4 + (threadIdx.x >> 6);
    const int lane = threadIdx.x & 63;
    const int h = (row >> 10) & 15;
    const int n = row & (NN - 1);
    const float om = (lane < 32) ? omega[h * 32 + lane] : -omega[h * 32 + lane - 32];
    float sn, cs;
    sincosf((float)n * om, &sn, &cs);
    short* qrow = qb + (size_t)row * 128;
    short* krow = kb + (size_t)row * 128;
    const float qre = bf2f(qrow[lane]), qim = bf2f(qrow[lane + 64]);
    const float kre = bf2f(krow[lane]), kim = bf2f(krow[lane + 64]);
    float qs = fmaf(qre, qre, qim * qim);
    float ks = fmaf(kre, kre, kim * kim);
    qrow[lane]      = f2bf(qre * cs - qim * sn);
    qrow[lane + 64] = f2bf(qre * sn + qim * cs);
    krow[lane]      = f2bf(kre * cs - kim * sn);
    krow[lane + 64] = f2bf(kre * sn + kim * cs);
#pragma unroll
    for (int m2 = 1; m2 < 64; m2 <<= 1) {
        qs += __shfl_xor(qs, m2);
        ks += __shfl_xor(ks, m2);
    }
    if (lane == 0) { qn_[row] = qs; kn_[row] = ks; }
}

// ---------------------------------------------------------------------------
// MFMA flash attention. 4 waves, 64 Q-rows of one (b,h); wave w owns rows
// w*16..+15. Q-frags in REGISTERS (loaded once). K/V staged via
// global_load_lds; dt tables staged from precomputed global tbl (L2).
// LDS = 44.3 KB -> 3 blocks/CU.
// ---------------------------------------------------------------------------
__global__ __launch_bounds__(256) void attn_mfma(
    const short* __restrict__ qr, const short* __restrict__ kr,
    const short* __restrict__ vt,
    const float* __restrict__ qn, const float* __restrict__ kn,
    const float4* __restrict__ tbl,
    const float* __restrict__ tau_p, const float* __restrict__ nu_raw,
    short* __restrict__ y) {
    __shared__ __align__(16) short Ks[64 * 128];   // [row][k], 16B-chunk XOR swizzle
    __shared__ __align__(16) short Vs[128 * 64];   // [d][j],   16B-chunk XOR swizzle
    __shared__ __align__(16) short Ps[64 * 72];    // [row][col], pad 72
    __shared__ __align__(16) float4 sT[128];       // idx = dt-dt0+63
    __shared__ float sKn[64];

    const int bh = blockIdx.y;
    const int h  = bh & 15;
    const int it = (bh & 16) ? (15 - (int)blockIdx.x) : (int)blockIdx.x;
    const int i0 = it * 64;
    const int tid  = threadIdx.x;
    const int lane = tid & 63, w = tid >> 6;
    const int quad = lane >> 4, l15 = lane & 15;

    const float nu     = log1pf(expf(nu_raw[h]));
    const float coef   = -0.5f * tau_p[h] * (nu + 64.0f);
    const float inv_nu = 1.f / nu;

    const short* Qb  = qr + (size_t)bh * NN * 128;
    const short* Kb  = kr + (size_t)bh * NN * 128;
    const short* Vtb = vt + (size_t)bh * 128 * NN;

    // Q-fragments in registers: A[m=l15][k=quad*8+j], rows globally contiguous
    bf16x8 qf[4];
    const int arow = i0 + w * 16 + l15;
#pragma unroll
    for (int ks = 0; ks < 4; ++ks)
        qf[ks] = *(const bf16x8*)&Qb[(size_t)arow * 128 + ks * 32 + quad * 8];

    float mrow[4], lrow[4];
    f32x4 o[8];
#pragma unroll
    for (int r = 0; r < 4; ++r) { mrow[r] = -INFINITY; lrow[r] = 0.f; }
#pragma unroll
    for (int s = 0; s < 8; ++s) o[s] = (f32x4){0.f, 0.f, 0.f, 0.f};
    float qn4[4];
#pragma unroll
    for (int r = 0; r < 4; ++r)
        qn4[r] = qn[(size_t)bh * NN + i0 + w * 16 + quad * 4 + r];

    for (int jt = 0; jt <= it; ++jt) {
        const int j0 = jt * 64, dt0 = i0 - j0;
        // stage K tile [64 rows][128 k]
#pragma unroll
        for (int i = 0; i < 4; ++i) {
            const int c = i * 256 + tid, row = c >> 4, src = ((c & 15) ^ (row & 7)) * 8;
            GLDS16(Kb + (size_t)(j0 + row) * 128 + src, &Ks[c * 8]);
        }
        // stage V tile [128 d][64 j]
#pragma unroll
        for (int i = 0; i < 4; ++i) {
            const int c = i * 256 + tid, d = c >> 3, src = ((c & 7) ^ (d & 7)) * 8;
            GLDS16(Vtb + (size_t)d * NN + j0 + src, &Vs[c * 8]);
        }
        // stage dt-table window (wave 0) and column norms (wave 1)
        if (w == 0) {
#pragma unroll
            for (int i = 0; i < 2; ++i)
                GLDS16(tbl + h * TBLR + 1 + dt0 + i * 64 + lane, &sT[i * 64 + lane]);
        } else if (w == 1) {
            GLDS4(kn + (size_t)bh * NN + j0 + lane, &sKn[lane]);
        }
        __syncthreads();

        // -------- S = Q @ K^T --------
        f32x4 sAcc[4];
#pragma unroll
        for (int s = 0; s < 4; ++s) sAcc[s] = (f32x4){0.f, 0.f, 0.f, 0.f};
#pragma unroll
        for (int ks = 0; ks < 4; ++ks) {
#pragma unroll
            for (int s = 0; s < 4; ++s) {
                const int brow = s * 16 + l15;
                bf16x8 bK = *(const bf16x8*)&Ks[brow * 128 + (((ks * 4 + quad) ^ (brow & 7)) * 8)];
                sAcc[s] = __builtin_amdgcn_mfma_f32_16x16x32_bf16(qf[ks], bK, sAcc[s], 0, 0, 0);
            }
        }

        // -------- softmax on C-layout (row = w*16+quad*4+r, col = s*16+l15) --------
        float al[4];
#pragma unroll
        for (int r = 0; r < 4; ++r) {
            const int row = w * 16 + quad * 4 + r;
            float lg[4];
            float mx = -INFINITY;
#pragma unroll
            for (int s = 0; s < 4; ++s) {
                const int col = s * 16 + l15;
                const float4 T = sT[row - col + 63];
                const float sv = sAcc[s][r];
                const float maha =
                    fmaxf(fmaf(T.x * T.x, sKn[col], qn4[r]) - 2.f * T.x * sv, 0.f) * T.y;
                float v = fmaf(coef, __logf(fmaf(maha, inv_nu, 1.f)), T.z);
                if (jt == it && col > row) v = -INFINITY;
                lg[s] = v;
                mx = fmaxf(mx, v);
            }
            mx = fmaxf(mx, __shfl_xor(mx, 1));
            mx = fmaxf(mx, __shfl_xor(mx, 2));
            mx = fmaxf(mx, __shfl_xor(mx, 4));
            mx = fmaxf(mx, __shfl_xor(mx, 8));
            const float mn = fmaxf(mrow[r], mx);
            const float a_ = __expf(mrow[r] - mn);
            float rs = 0.f;
#pragma unroll
            for (int s = 0; s < 4; ++s) {
                const float p = __expf(lg[s] - mn);
                Ps[row * 72 + s * 16 + l15] = f2bf(p);
                rs += p;
            }
            rs += __shfl_xor(rs, 1);
            rs += __shfl_xor(rs, 2);
            rs += __shfl_xor(rs, 4);
            rs += __shfl_xor(rs, 8);
            lrow[r] = fmaf(lrow[r], a_, rs);
            mrow[r] = mn;
            al[r] = a_;
        }
#pragma unroll
        for (int s = 0; s < 8; ++s)
#pragma unroll
            for (int r = 0; r < 4; ++r) o[s][r] *= al[r];

        // -------- O += P @ V (P rows own-wave only: no barrier needed) --------
#pragma unroll
        for (int jc = 0; jc < 2; ++jc) {
            bf16x8 aP = *(const bf16x8*)&Ps[(w * 16 + l15) * 72 + jc * 32 + quad * 8];
#pragma unroll
            for (int sub = 0; sub < 8; ++sub) {
                const int d = sub * 16 + l15;
                bf16x8 bV = *(const bf16x8*)&Vs[d * 64 + (((jc * 4 + quad) ^ (d & 7)) * 8)];
                o[sub] = __builtin_amdgcn_mfma_f32_16x16x32_bf16(aP, bV, o[sub], 0, 0, 0);
            }
        }
        __syncthreads();   // protect Ks/Vs/sT/sKn before next tile's staging
    }

    // -------- epilogue: O/l -> bf16 packed y --------
#pragma unroll
    for (int r = 0; r < 4; ++r) {
        const float inv = 1.f / lrow[r];
        const size_t base = ((size_t)bh * NN + i0 + w * 16 + quad * 4 + r) * 128;
#pragma unroll
        for (int sub = 0; sub < 8; ++sub)
            y[base + sub * 16 + l15] = f2bf(o[sub][r] * inv);
    }
}

// ---------------------------------------------------------------------------
extern "C" void kernel_launch(void* const* d_in, const int* in_sizes, int n_in,
                              void* d_out, int out_size, void* d_ws, size_t ws_size,
                              hipStream_t stream) {
    const float* x         = (const float*)d_in[0];
    const float* Wq        = (const float*)d_in[1];
    const float* Wk        = (const float*)d_in[2];
    const float* Wv        = (const float*)d_in[3];
    const float* Wo        = (const float*)d_in[4];
    const float* omega     = (const float*)d_in[5];
    const float* mu_raw    = (const float*)d_in[6];
    const float* sigma_raw = (const float*)d_in[7];
    const float* eta_raw   = (const float*)d_in[8];
    const float* gamma_raw = (const float*)d_in[9];
    const float* tau       = (const float*)d_in[10];
    const float* nu_raw    = (const float*)d_in[11];
    float* out = (float*)d_out;

    // ws layout (~55 MB): qb | kb | vtb (bf16, PK each) | qn | kn (f32) |
    // tbl (float4) | wot | wt x3 | xb (bf16).  yb aliases wt.
    short*  qb  = (short*)d_ws;
    short*  kb  = qb + PK;
    short*  vtb = kb + PK;
    float*  qn  = (float*)(vtb + PK);
    float*  kn  = qn + 32768;
    float4* tbl = (float4*)(kn + 32768);
    short*  wot = (short*)(tbl + HH * TBLR);
    short*  wt  = wot + 2097152;
    short*  xb  = wt + 3 * 2097152;
    short*  yb  = wt;                               // alias

    f32_to_bf16<<<dim3(2048), 256, 0, stream>>>(x, xb, 2097152);
    transpose_bf16<<<dim3(32, 32, 4), 256, 0, stream>>>(Wq, Wk, Wv, Wo, wt, wot);
    tbl_precomp<<<dim3(5, 16), 256, 0, stream>>>(
        mu_raw, sigma_raw, eta_raw, gamma_raw, tbl);
    // q,k packed bf16; V emitted transposed (z==2) via 8B stores
    gemm_mfma<1024, 2048, false, 1><<<dim3(16, 16, 3), 256, 0, stream>>>(
        xb, wt, nullptr, qb, vtb, (size_t)2097152);
    rotate_qk<<<dim3(8192), 256, 0, stream>>>(qb, kb, omega, qn, kn);
    attn_mfma<<<dim3(16, 32), 256, 0, stream>>>(
        qb, kb, vtb, qn, kn, tbl, tau, nu_raw, yb);
    hipMemsetAsync(out, 0, (size_t)out_size * sizeof(float), stream);
    gemm_mfma<2048, 1024, true, 2><<<dim3(16, 8, 4), 256, 0, stream>>>(
        yb, wot, out, nullptr, nullptr, 0);
}